// Round 5
// baseline (5000.693 us; speedup 1.0000x reference)
//
#include <hip/hip_runtime.h>
#include <hip/hip_bf16.h>

// ---------- types ----------
typedef __attribute__((ext_vector_type(8))) short short8;
typedef __attribute__((ext_vector_type(4))) float f32x4;

#define MROWS 4096      // b*l
#define CDIM  1024
#define HEADS 16
#define DHEAD 64
#define NSEQ  1024

// ---------- small device helpers ----------
__device__ inline float softw(const float* __restrict__ w, int idx) {
    // softmax(w/0.01)[idx] over 6 entries
    float m = w[0];
#pragma unroll
    for (int i = 1; i < 6; i++) m = fmaxf(m, w[i]);
    float s = 0.f, v = 0.f;
#pragma unroll
    for (int i = 0; i < 6; i++) {
        float e = __expf((w[i] - m) * 100.0f);
        s += e;
        if (i == idx) v = e;
    }
    return v / s;
}

__device__ inline float gelu_f(float x) {
    return 0.5f * x * (1.0f + erff(x * 0.70710678118654752f));
}

__device__ inline float wred_sum(float v) {
#pragma unroll
    for (int m = 1; m < 64; m <<= 1) v += __shfl_xor(v, m, 64);
    return v;
}

// ---------- prologue: x -> bf16, zero attn-map accumulator ----------
__global__ __launch_bounds__(256) void mix_base(
    const float* __restrict__ x_list, __hip_bfloat16* __restrict__ xb,
    float* __restrict__ am_acc)
{
    int i = blockIdx.x * 256 + threadIdx.x;   // 0 .. 4M-1
    xb[i] = __float2bfloat16(x_list[2 * (size_t)i + 1]);
    if (i < 4096) am_acc[i] = 0.f;
}

// ---------- fp32 -> bf16 weight convert ----------
__global__ __launch_bounds__(256) void f2b(const float* __restrict__ in,
                                           __hip_bfloat16* __restrict__ out, int n)
{
    int i = blockIdx.x * 256 + threadIdx.x;
    if (i < n) out[i] = __float2bfloat16(in[i]);
}

// ---------- bf16 MFMA GEMM, dbuf LDS + depth-2 register prefetch ----------
// C[m,n] = sum_k A[m,k]*W[n,k] (+epilogue). 4 waves as 2x2.
// EPI: 1=conv(base mix from x_list + w2*gelu -> f0), 2=mlp1(gelu->bf16),
//      3=mlp2(final mix, f32+bf16), 4=proj(+bias+res -> f0),
//      5=qkv(fused per-head LN: q->b1, k->b2 bf16 [b,h,n,d]; v->b0 V^T bf16)
#define BKT 32
#define LDA 40   // 32 + 8 pad (16B aligned, 2-way LDS banks = free)

template<int EPI, int FM, int FN>
__global__ __launch_bounds__(256) void gemm_bf16(
    const __hip_bfloat16* __restrict__ A, const __hip_bfloat16* __restrict__ W,
    const float* __restrict__ bias,
    float* __restrict__ f0, float* __restrict__ f1,
    __hip_bfloat16* __restrict__ b0, __hip_bfloat16* __restrict__ b1,
    __hip_bfloat16* __restrict__ b2,
    const float* __restrict__ g0, const float* __restrict__ be0,
    const float* __restrict__ g1, const float* __restrict__ be1,
    const float* __restrict__ wvec, int M, int N, int K)
{
    constexpr int BMt = FM * 32;
    constexpr int BNt = FN * 32;
    constexpr int NA = BMt / 64;    // short8 staged per thread (A)
    constexpr int NB = BNt / 64;    // short8 staged per thread (B)
    __shared__ __hip_bfloat16 As[2][BMt * LDA];
    __shared__ __hip_bfloat16 Bs[2][BNt * LDA];
    int t = threadIdx.x;
    int n0 = blockIdx.x * BNt, m0 = blockIdx.y * BMt;
    int wave = t >> 6, lane = t & 63;
    int wr = wave >> 1, wc = wave & 1;
    int quad = lane >> 4, l16 = lane & 15;
    int r0 = t >> 2, c0 = (t & 3) * 8;    // staging: 4 lanes/row, 64 rows/round

    short8 sa[2][NA], sb[2][NB];
    auto ldg = [&](int k0, short8* da, short8* db) {
#pragma unroll
        for (int i = 0; i < NA; i++)
            da[i] = *(const short8*)(A + (size_t)(m0 + r0 + 64 * i) * K + k0 + c0);
#pragma unroll
        for (int i = 0; i < NB; i++)
            db[i] = *(const short8*)(W + (size_t)(n0 + r0 + 64 * i) * K + k0 + c0);
    };
    ldg(0, sa[0], sb[0]);
    ldg(BKT, sa[1], sb[1]);

    f32x4 zero = {0.f, 0.f, 0.f, 0.f};
    f32x4 acc[FM][FN];
#pragma unroll
    for (int i = 0; i < FM; i++)
#pragma unroll
        for (int j = 0; j < FN; j++) acc[i][j] = zero;

    int buf = 0, st = 0;
    for (int k0 = 0; k0 < K; k0 += BKT) {
#pragma unroll
        for (int i = 0; i < NA; i++)
            *(short8*)&As[buf][(r0 + 64 * i) * LDA + c0] = sa[st][i];
#pragma unroll
        for (int i = 0; i < NB; i++)
            *(short8*)&Bs[buf][(r0 + 64 * i) * LDA + c0] = sb[st][i];
        __syncthreads();
        if (k0 + 2 * BKT < K) ldg(k0 + 2 * BKT, sa[st], sb[st]);  // 2-deep pipeline
        short8 af[FM], bf[FN];
#pragma unroll
        for (int i = 0; i < FM; i++)
            af[i] = *(const short8*)&As[buf][(wr * FM * 16 + i * 16 + l16) * LDA + quad * 8];
#pragma unroll
        for (int j = 0; j < FN; j++)
            bf[j] = *(const short8*)&Bs[buf][(wc * FN * 16 + j * 16 + l16) * LDA + quad * 8];
#pragma unroll
        for (int i = 0; i < FM; i++)
#pragma unroll
            for (int j = 0; j < FN; j++)
                acc[i][j] = __builtin_amdgcn_mfma_f32_16x16x32_bf16(
                    af[i], bf[j], acc[i][j], 0, 0, 0);
        buf ^= 1; st ^= 1;   // single barrier/iter: dbuf + rendezvous keeps it safe
    }

    if constexpr (EPI == 5) {
        int colbase = n0 + wc * FN * 16;           // 64-aligned => one head per wave
        int portion = colbase >> 10;               // 0=q 1=k 2=v
        int hh = (colbase >> 6) & 15;
        float bv[FN];
#pragma unroll
        for (int j = 0; j < FN; j++) bv[j] = bias[colbase + j * 16 + l16];
        if (portion == 2) {
#pragma unroll
            for (int i = 0; i < FM; i++)
#pragma unroll
                for (int j = 0; j < FN; j++)
#pragma unroll
                    for (int r = 0; r < 4; r++) {
                        int row = m0 + wr * FM * 16 + i * 16 + quad * 4 + r;
                        int bb = row >> 10, nn = row & 1023;
                        int dd = j * 16 + l16;
                        b0[((size_t)(bb * 16 + hh) * DHEAD + dd) * NSEQ + nn] =
                            __float2bfloat16(acc[i][j][r] + bv[j]);
                    }
        } else {
            const float* g  = (portion == 0) ? g0 : g1;
            const float* be = (portion == 0) ? be0 : be1;
            __hip_bfloat16* dst = (portion == 0) ? b1 : b2;
            float gv[FN], bev[FN];
#pragma unroll
            for (int j = 0; j < FN; j++) {
                gv[j] = g[j * 16 + l16];
                bev[j] = be[j * 16 + l16];
            }
#pragma unroll
            for (int i = 0; i < FM; i++)
#pragma unroll
                for (int r = 0; r < 4; r++) {
                    float s1 = 0.f, s2 = 0.f;
#pragma unroll
                    for (int j = 0; j < FN; j++) {
                        float v = acc[i][j][r] + bv[j];
                        s1 += v; s2 += v * v;
                    }
#pragma unroll
                    for (int mk = 1; mk < 16; mk <<= 1) {
                        s1 += __shfl_xor(s1, mk, 64);
                        s2 += __shfl_xor(s2, mk, 64);
                    }
                    float mean = s1 * (1.f / 64.f);
                    float var = s2 * (1.f / 64.f) - mean * mean;
                    float rs = rsqrtf(var + 1e-5f);
                    int row = m0 + wr * FM * 16 + i * 16 + quad * 4 + r;
                    int bb = row >> 10, nn = row & 1023;
                    size_t base = ((size_t)(bb * 16 + hh) * NSEQ + nn) * DHEAD;
#pragma unroll
                    for (int j = 0; j < FN; j++)
                        dst[base + j * 16 + l16] = __float2bfloat16(
                            (acc[i][j][r] + bv[j] - mean) * rs * gv[j] + bev[j]);
                }
        }
        return;
    }

    float wmx = 0.f, w0c = 0.f, w14c = 0.f;
    if (EPI == 1) {
        wmx = softw(wvec, 2);
        w0c = softw(wvec, 0);
        w14c = softw(wvec, 1) + softw(wvec, 4);
    }
    if (EPI == 3) wmx = softw(wvec, 5);

#pragma unroll
    for (int i = 0; i < FM; i++) {
#pragma unroll
        for (int j = 0; j < FN; j++) {
            int col = n0 + wc * FN * 16 + j * 16 + l16;
            float bv = bias[col];
#pragma unroll
            for (int r = 0; r < 4; r++) {
                int row = m0 + wr * FM * 16 + i * 16 + quad * 4 + r;
                float v = acc[i][j][r] + bv;
                size_t idx = (size_t)row * N + col;
                if (EPI == 1) {
                    float2 xl = *((const float2*)f1 + idx);   // x_list pair
                    f0[idx] = w0c * xl.x + w14c * xl.y + wmx * gelu_f(v);
                } else if (EPI == 2) {
                    b0[idx] = __float2bfloat16(gelu_f(v));    // mlp hidden
                } else if (EPI == 3) {
                    float tv = f0[idx] + wmx * v;             // final mix
                    f0[idx] = tv;
                    b0[idx] = __float2bfloat16(tv);
                } else if (EPI == 4) {
                    f0[idx] = v + f1[idx];                    // proj + residual
                }
            }
        }
    }
}

// ---------- ca1: h1 = relu(x @ ca1_w^T + b)  [4096,64], K=1024, x bf16 ----------
__global__ __launch_bounds__(256) void ca1_kernel(
    const __hip_bfloat16* __restrict__ xb, const float* __restrict__ w,
    const float* __restrict__ bias, float* __restrict__ h1)
{
    __shared__ float Xs[16 * 65];
    __shared__ float Ws[64 * 65];
    int t = threadIdx.x;
    int m0 = blockIdx.x * 16;
    int row = t >> 4, cg = t & 15;
    float acc[4] = {0.f, 0.f, 0.f, 0.f};
    for (int k0 = 0; k0 < 1024; k0 += 64) {
#pragma unroll
        for (int i = 0; i < 4; i++) {
            int e = t + i * 256; int r = e >> 6, c = e & 63;
            Xs[r * 65 + c] = __bfloat162float(xb[(size_t)(m0 + r) * 1024 + k0 + c]);
        }
#pragma unroll
        for (int i = 0; i < 16; i++) {
            int e = t + i * 256; int r = e >> 6, c = e & 63;
            Ws[r * 65 + c] = w[(size_t)r * 1024 + k0 + c];
        }
        __syncthreads();
        for (int k = 0; k < 64; k++) {
            float xv = Xs[row * 65 + k];
#pragma unroll
            for (int c = 0; c < 4; c++)
                acc[c] += xv * Ws[(cg * 4 + c) * 65 + k];
        }
        __syncthreads();
    }
#pragma unroll
    for (int c = 0; c < 4; c++)
        h1[(size_t)(m0 + row) * 64 + cg * 4 + c] =
            fmaxf(acc[c] + bias[cg * 4 + c], 0.f);
}

// ---------- ca2: xmix += w3 * sigmoid(h1 @ ca2_w^T + b) * x ----------
__global__ __launch_bounds__(256) void ca2_kernel(
    const float* __restrict__ h1, const float* __restrict__ w,
    const float* __restrict__ bias, const __hip_bfloat16* __restrict__ xb,
    float* __restrict__ xmix, const float* __restrict__ wvec)
{
    __shared__ float Wt[256 * 65];
    __shared__ float hs[16 * 64];
    int t = threadIdx.x;
    int m0 = blockIdx.x * 16, n0 = blockIdx.y * 256;
#pragma unroll
    for (int i = 0; i < 64; i++) {
        int e = t + i * 256; int r = e >> 6, c = e & 63;
        Wt[r * 65 + c] = w[(size_t)(n0 + r) * 64 + c];
    }
#pragma unroll
    for (int i = 0; i < 4; i++) {
        int e = t + i * 256; int r = e >> 6, c = e & 63;
        hs[r * 64 + c] = h1[(size_t)(m0 + r) * 64 + c];
    }
    __syncthreads();
    int n = n0 + t;
    float bv = bias[n];
    float acc[16];
#pragma unroll
    for (int mi = 0; mi < 16; mi++) acc[mi] = bv;
    for (int k = 0; k < 64; k++) {
        float wv = Wt[t * 65 + k];
#pragma unroll
        for (int mi = 0; mi < 16; mi++) acc[mi] += hs[mi * 64 + k] * wv;
    }
    float w3 = softw(wvec, 3);
#pragma unroll
    for (int mi = 0; mi < 16; mi++) {
        size_t idx = (size_t)(m0 + mi) * 1024 + n;
        float sg = 1.f / (1.f + __expf(-acc[mi]));
        xmix[idx] += w3 * sg * __bfloat162float(xb[idx]);
    }
}

// ---------- MFMA flash attention ----------
// grid (64 bh, 8 i-tiles), block 256 (4 waves). Wave owns 32 q-rows.
// Q/K bf16 [b,h,n,d]; V^T bf16 [b,h,d,n]; out ao bf16 [b,n,c].
// K/V fragments read direct from global (L2-resident per bh).
// P round-trips through wave-private LDS (no barriers in kernel).
#define PSTR 72   // bf16 stride: 144 B, 16B-aligned, 2-way banks
__global__ __launch_bounds__(256) void flash_mfma(
    const __hip_bfloat16* __restrict__ qb, const __hip_bfloat16* __restrict__ kb,
    const __hip_bfloat16* __restrict__ vt, __hip_bfloat16* __restrict__ ao)
{
    __shared__ __hip_bfloat16 Plds[4][32 * PSTR];
    int bh = blockIdx.x;
    int i0 = blockIdx.y * 128;
    int b = bh >> 4, h = bh & 15;
    int t = threadIdx.x, wave = t >> 6, lane = t & 63;
    int l16 = lane & 15, quad = lane >> 4;
    const __hip_bfloat16* qbase = qb + (size_t)bh * NSEQ * DHEAD;
    const __hip_bfloat16* kbase = kb + (size_t)bh * NSEQ * DHEAD;
    const __hip_bfloat16* vbase = vt + (size_t)bh * DHEAD * NSEQ;
    __hip_bfloat16* pw = Plds[wave];
    int qrow0 = i0 + wave * 32;

    // Q fragments, held for the whole kernel
    short8 aq[2][2];
#pragma unroll
    for (int ri = 0; ri < 2; ri++)
#pragma unroll
        for (int ks = 0; ks < 2; ks++)
            aq[ri][ks] = *(const short8*)(qbase +
                (size_t)(qrow0 + ri * 16 + l16) * DHEAD + ks * 32 + quad * 8);

    f32x4 zero = {0.f, 0.f, 0.f, 0.f};
    f32x4 o[2][4];
    float mrow[2][4], lrow[2][4];
#pragma unroll
    for (int ri = 0; ri < 2; ri++) {
#pragma unroll
        for (int nt = 0; nt < 4; nt++) o[ri][nt] = zero;
#pragma unroll
        for (int rr = 0; rr < 4; rr++) { mrow[ri][rr] = -1e30f; lrow[ri][rr] = 0.f; }
    }

    for (int j0 = 0; j0 < NSEQ; j0 += 64) {
        // K fragments: B[n=key][k=d]
        short8 bk[4][2];
#pragma unroll
        for (int jt = 0; jt < 4; jt++)
#pragma unroll
            for (int ks = 0; ks < 2; ks++)
                bk[jt][ks] = *(const short8*)(kbase +
                    (size_t)(j0 + jt * 16 + l16) * DHEAD + ks * 32 + quad * 8);
        // V^T fragments: B[n=d][k=key]
        short8 bv[4][2];
#pragma unroll
        for (int nt = 0; nt < 4; nt++)
#pragma unroll
            for (int ks = 0; ks < 2; ks++)
                bv[nt][ks] = *(const short8*)(vbase +
                    (size_t)(nt * 16 + l16) * NSEQ + j0 + ks * 32 + quad * 8);

#pragma unroll
        for (int ri = 0; ri < 2; ri++) {
            f32x4 s[4];
#pragma unroll
            for (int jt = 0; jt < 4; jt++) s[jt] = zero;
#pragma unroll
            for (int jt = 0; jt < 4; jt++)
#pragma unroll
                for (int ks = 0; ks < 2; ks++)
                    s[jt] = __builtin_amdgcn_mfma_f32_16x16x32_bf16(
                        aq[ri][ks], bk[jt][ks], s[jt], 0, 0, 0);
            // online softmax, row = quad*4+rr (C-layout), col = jt*16+l16
#pragma unroll
            for (int rr = 0; rr < 4; rr++) {
                float mx = -1e30f;
#pragma unroll
                for (int jt = 0; jt < 4; jt++) {
                    s[jt][rr] *= 0.125f;
                    mx = fmaxf(mx, s[jt][rr]);
                }
#pragma unroll
                for (int mk = 1; mk < 16; mk <<= 1) mx = fmaxf(mx, __shfl_xor(mx, mk, 64));
                float om = mrow[ri][rr];
                float nm = fmaxf(om, mx);
                float al = __expf(om - nm);
                mrow[ri][rr] = nm;
                float ss = 0.f;
#pragma unroll
                for (int jt = 0; jt < 4; jt++) {
                    float p = __expf(s[jt][rr] - nm);
                    pw[(ri * 16 + quad * 4 + rr) * PSTR + jt * 16 + l16] =
                        __float2bfloat16(p);
                    ss += p;
                }
#pragma unroll
                for (int mk = 1; mk < 16; mk <<= 1) ss += __shfl_xor(ss, mk, 64);
                lrow[ri][rr] = lrow[ri][rr] * al + ss;
#pragma unroll
                for (int nt = 0; nt < 4; nt++) o[ri][nt][rr] *= al;
            }
        }
        // PV: A = P from wave-private LDS (compiler inserts lgkmcnt wait)
#pragma unroll
        for (int ri = 0; ri < 2; ri++) {
            short8 ap[2];
#pragma unroll
            for (int ks = 0; ks < 2; ks++)
                ap[ks] = *(const short8*)&pw[(ri * 16 + l16) * PSTR + ks * 32 + quad * 8];
#pragma unroll
            for (int nt = 0; nt < 4; nt++)
#pragma unroll
                for (int ks = 0; ks < 2; ks++)
                    o[ri][nt] = __builtin_amdgcn_mfma_f32_16x16x32_bf16(
                        ap[ks], bv[nt][ks], o[ri][nt], 0, 0, 0);
        }
    }

#pragma unroll
    for (int ri = 0; ri < 2; ri++)
#pragma unroll
        for (int rr = 0; rr < 4; rr++) {
            float inv = 1.f / lrow[ri][rr];
            int row = qrow0 + ri * 16 + quad * 4 + rr;
#pragma unroll
            for (int nt = 0; nt < 4; nt++)
                ao[((size_t)b * NSEQ + row) * CDIM + h * 64 + nt * 16 + l16] =
                    __float2bfloat16(o[ri][nt][rr] * inv);
        }
}

// ---------- attn_map: mean over heads of attn[:,0,1:] ----------
__global__ __launch_bounds__(256) void attn_map_acc(
    const __hip_bfloat16* __restrict__ qf, const __hip_bfloat16* __restrict__ kf,
    float* __restrict__ am)
{
    __shared__ float q0[64];
    __shared__ float red[256];
    int bh = blockIdx.x, t = threadIdx.x;
    const __hip_bfloat16* qr = qf + (size_t)bh * NSEQ * DHEAD;   // row 0
    const __hip_bfloat16* kb = kf + (size_t)bh * NSEQ * DHEAD;
    if (t < 64) q0[t] = __bfloat162float(qr[t]);
    __syncthreads();
    float s[4];
    float mx = -1e30f;
#pragma unroll
    for (int ji = 0; ji < 4; ji++) {
        int j = ji * 256 + t;
        float a = 0.f;
        for (int k = 0; k < 64; k++) a += q0[k] * __bfloat162float(kb[(size_t)j * 64 + k]);
        a *= 0.125f;
        s[ji] = a;
        mx = fmaxf(mx, a);
    }
    red[t] = mx; __syncthreads();
    for (int st = 128; st > 0; st >>= 1) {
        if (t < st) red[t] = fmaxf(red[t], red[t + st]);
        __syncthreads();
    }
    float M = red[0]; __syncthreads();
    float sum = 0.f;
#pragma unroll
    for (int ji = 0; ji < 4; ji++) { s[ji] = __expf(s[ji] - M); sum += s[ji]; }
    red[t] = sum; __syncthreads();
    for (int st = 128; st > 0; st >>= 1) {
        if (t < st) red[t] += red[t + st];
        __syncthreads();
    }
    float inv = 1.f / red[0];
    int b = bh >> 4;
#pragma unroll
    for (int ji = 0; ji < 4; ji++) {
        int j = ji * 256 + t;
        if (j > 0) atomicAdd(&am[b * 1024 + j], s[ji] * inv * (1.f / 16.f));
    }
}

__global__ __launch_bounds__(256) void attn_map_out(
    const float* __restrict__ am, float* __restrict__ out1)
{
    int i = blockIdx.x * 256 + threadIdx.x;
    if (i < 4 * 1023) {
        int b = i / 1023;
        int j = i - b * 1023 + 1;
        out1[i] = am[b * 1024 + j];
    }
}

// ---------- launch ----------
extern "C" void kernel_launch(void* const* d_in, const int* in_sizes, int n_in,
                              void* d_out, int out_size, void* d_ws, size_t ws_size,
                              hipStream_t stream)
{
    const float* x_list = (const float*)d_in[0];
    const float* wvec   = (const float*)d_in[1];
    const float* qkv_w  = (const float*)d_in[2];
    const float* qkv_b  = (const float*)d_in[3];
    const float* proj_w = (const float*)d_in[4];
    const float* proj_b = (const float*)d_in[5];
    const float* nq_g   = (const float*)d_in[6];
    const float* nq_b   = (const float*)d_in[7];
    const float* nk_g   = (const float*)d_in[8];
    const float* nk_b   = (const float*)d_in[9];
    const float* conv_w = (const float*)d_in[10];
    const float* conv_b = (const float*)d_in[11];
    const float* ca1_w  = (const float*)d_in[12];
    const float* ca1_b  = (const float*)d_in[13];
    const float* ca2_w  = (const float*)d_in[14];
    const float* ca2_b  = (const float*)d_in[15];
    const float* mlp1_w = (const float*)d_in[16];
    const float* mlp1_b = (const float*)d_in[17];
    const float* mlp2_w = (const float*)d_in[18];
    const float* mlp2_b = (const float*)d_in[19];

    float* out0 = (float*)d_out;
    float* out1 = out0 + (size_t)4 * 1024 * 1024;

    char* ws = (char*)d_ws;
    size_t off = 0;
    auto alloc = [&](size_t bytes) -> char* {
        char* p = ws + off;
        off += (bytes + 255) & ~(size_t)255;
        return p;
    };
    __hip_bfloat16* xb     = (__hip_bfloat16*)alloc((size_t)MROWS * CDIM * 2);
    float*          xmix   = (float*)alloc((size_t)MROWS * CDIM * 4);
    __hip_bfloat16* xmixb  = (__hip_bfloat16*)alloc((size_t)MROWS * CDIM * 2);
    float*          h1     = (float*)alloc((size_t)MROWS * 64 * 4);
    __hip_bfloat16* hb     = (__hip_bfloat16*)alloc((size_t)MROWS * 4096 * 2);
    __hip_bfloat16* qbb    = (__hip_bfloat16*)alloc((size_t)MROWS * CDIM * 2);
    __hip_bfloat16* kbb    = (__hip_bfloat16*)alloc((size_t)MROWS * CDIM * 2);
    __hip_bfloat16* vtb    = (__hip_bfloat16*)alloc((size_t)MROWS * CDIM * 2);
    __hip_bfloat16* aob    = (__hip_bfloat16*)alloc((size_t)MROWS * CDIM * 2);
    float*          amacc  = (float*)alloc(4096 * 4);
    __hip_bfloat16* convwb = (__hip_bfloat16*)alloc((size_t)1048576 * 2);
    __hip_bfloat16* qkvwb  = (__hip_bfloat16*)alloc((size_t)3145728 * 2);
    __hip_bfloat16* projwb = (__hip_bfloat16*)alloc((size_t)1048576 * 2);
    __hip_bfloat16* mlp1wb = (__hip_bfloat16*)alloc((size_t)4194304 * 2);
    __hip_bfloat16* mlp2wb = (__hip_bfloat16*)alloc((size_t)4194304 * 2);

    // weight converts
    f2b<<<4096, 256, 0, stream>>>(conv_w, convwb, 1048576);
    f2b<<<12288, 256, 0, stream>>>(qkv_w, qkvwb, 3145728);
    f2b<<<4096, 256, 0, stream>>>(proj_w, projwb, 1048576);
    f2b<<<16384, 256, 0, stream>>>(mlp1_w, mlp1wb, 4194304);
    f2b<<<16384, 256, 0, stream>>>(mlp2_w, mlp2wb, 4194304);

    // prologue: x -> bf16 only
    mix_base<<<16384, 256, 0, stream>>>(x_list, xb, amacc);

    // op0: conv (gelu) epilogue also writes base mix from x_list
    gemm_bf16<1, 4, 2><<<dim3(16, 32), 256, 0, stream>>>(
        xb, convwb, conv_b, xmix, (float*)x_list, nullptr, nullptr, nullptr,
        nullptr, nullptr, nullptr, nullptr, wvec, MROWS, 1024, 1024);

    // op1: channel attention (must follow conv's xmix write)
    ca1_kernel<<<256, 256, 0, stream>>>(xb, ca1_w, ca1_b, h1);
    ca2_kernel<<<dim3(256, 4), 256, 0, stream>>>(h1, ca2_w, ca2_b, xb, xmix, wvec);

    // op3: MLP
    gemm_bf16<2, 4, 4><<<dim3(32, 32), 256, 0, stream>>>(
        xb, mlp1wb, mlp1_b, nullptr, nullptr, hb, nullptr, nullptr,
        nullptr, nullptr, nullptr, nullptr, wvec, MROWS, 4096, 1024);
    gemm_bf16<3, 4, 2><<<dim3(16, 32), 256, 0, stream>>>(
        hb, mlp2wb, mlp2_b, xmix, nullptr, xmixb, nullptr, nullptr,
        nullptr, nullptr, nullptr, nullptr, wvec, MROWS, 1024, 4096);

    // qkv with fused per-head LN: q->qbb, k->kbb bf16 [b,h,n,d]; v->V^T bf16
    gemm_bf16<5, 4, 4><<<dim3(24, 32), 256, 0, stream>>>(
        xmixb, qkvwb, qkv_b, nullptr, nullptr, vtb, qbb, kbb,
        nq_g, nq_b, nk_g, nk_b, wvec, MROWS, 3072, 1024);

    // attention (MFMA)
    flash_mfma<<<dim3(64, 8), 256, 0, stream>>>(qbb, kbb, vtb, aob);

    // attn_map
    attn_map_acc<<<64, 256, 0, stream>>>(qbb, kbb, amacc);
    attn_map_out<<<16, 256, 0, stream>>>(amacc, out1);

    // projection + residual
    gemm_bf16<4, 4, 2><<<dim3(16, 32), 256, 0, stream>>>(
        aob, projwb, proj_b, out0, xmix, nullptr, nullptr, nullptr,
        nullptr, nullptr, nullptr, nullptr, wvec, MROWS, 1024, 1024);
}

// Round 6
// 548.795 us; speedup vs baseline: 9.1121x; 9.1121x over previous
//
#include <hip/hip_runtime.h>
#include <hip/hip_bf16.h>

// ---------- types ----------
typedef __attribute__((ext_vector_type(8))) short short8;
typedef __attribute__((ext_vector_type(4))) float f32x4;

#define MROWS 4096      // b*l
#define CDIM  1024
#define HEADS 16
#define DHEAD 64
#define NSEQ  1024

// ---------- small device helpers ----------
__device__ inline float softw(const float* __restrict__ w, int idx) {
    // softmax(w/0.01)[idx] over 6 entries
    float m = w[0];
#pragma unroll
    for (int i = 1; i < 6; i++) m = fmaxf(m, w[i]);
    float s = 0.f, v = 0.f;
#pragma unroll
    for (int i = 0; i < 6; i++) {
        float e = __expf((w[i] - m) * 100.0f);
        s += e;
        if (i == idx) v = e;
    }
    return v / s;
}

__device__ inline float gelu_f(float x) {
    return 0.5f * x * (1.0f + erff(x * 0.70710678118654752f));
}

// ---------- prologue: x -> bf16, zero attn-map accumulator ----------
__global__ __launch_bounds__(256) void mix_base(
    const float* __restrict__ x_list, __hip_bfloat16* __restrict__ xb,
    float* __restrict__ am_acc)
{
    int i = blockIdx.x * 256 + threadIdx.x;   // 0 .. 4M-1
    xb[i] = __float2bfloat16(x_list[2 * (size_t)i + 1]);
    if (i < 4096) am_acc[i] = 0.f;
}

// ---------- fp32 -> bf16 weight convert ----------
__global__ __launch_bounds__(256) void f2b(const float* __restrict__ in,
                                           __hip_bfloat16* __restrict__ out, int n)
{
    int i = blockIdx.x * 256 + threadIdx.x;
    if (i < n) out[i] = __float2bfloat16(in[i]);
}

// ---------- bf16 MFMA GEMM, dbuf LDS + depth-2 register prefetch ----------
// Manually 2x-unrolled K-loop: ALL private arrays statically indexed (the
// round-5 dynamic-index version spilled staging buffers to scratch: 28x slower).
// EPI: 1=conv(base mix from x_list + w2*gelu -> f0), 2=mlp1(gelu->bf16),
//      3=mlp2(final mix, f32+bf16), 4=proj(+bias+res -> f0),
//      5=qkv(fused per-head LN: q->b1, k->b2 bf16 [b,h,n,d]; v->b0 V^T bf16)
#define BKT 32
#define LDA 40   // 32 + 8 pad (16B aligned, 2-way LDS banks = free)

template<int EPI, int FM, int FN>
__global__ __launch_bounds__(256) void gemm_bf16(
    const __hip_bfloat16* __restrict__ A, const __hip_bfloat16* __restrict__ W,
    const float* __restrict__ bias,
    float* __restrict__ f0, float* __restrict__ f1,
    __hip_bfloat16* __restrict__ b0, __hip_bfloat16* __restrict__ b1,
    __hip_bfloat16* __restrict__ b2,
    const float* __restrict__ g0, const float* __restrict__ be0,
    const float* __restrict__ g1, const float* __restrict__ be1,
    const float* __restrict__ wvec, int M, int N, int K)
{
    constexpr int BMt = FM * 32;
    constexpr int BNt = FN * 32;
    constexpr int NA = BMt / 64;    // short8 staged per thread (A)
    constexpr int NB = BNt / 64;    // short8 staged per thread (B)
    __shared__ __hip_bfloat16 As[2][BMt * LDA];
    __shared__ __hip_bfloat16 Bs[2][BNt * LDA];
    int t = threadIdx.x;
    int n0 = blockIdx.x * BNt, m0 = blockIdx.y * BMt;
    int wave = t >> 6, lane = t & 63;
    int wr = wave >> 1, wc = wave & 1;
    int quad = lane >> 4, l16 = lane & 15;
    int r0 = t >> 2, c0 = (t & 3) * 8;    // staging: 4 lanes/row, 64 rows/round

    short8 sa0[NA], sb0[NB], sa1[NA], sb1[NB];
    auto ldg = [&](int k0, short8* da, short8* db) {
#pragma unroll
        for (int i = 0; i < NA; i++)
            da[i] = *(const short8*)(A + (size_t)(m0 + r0 + 64 * i) * K + k0 + c0);
#pragma unroll
        for (int i = 0; i < NB; i++)
            db[i] = *(const short8*)(W + (size_t)(n0 + r0 + 64 * i) * K + k0 + c0);
    };
    ldg(0, sa0, sb0);
    ldg(BKT, sa1, sb1);

    f32x4 zero = {0.f, 0.f, 0.f, 0.f};
    f32x4 acc[FM][FN];
#pragma unroll
    for (int i = 0; i < FM; i++)
#pragma unroll
        for (int j = 0; j < FN; j++) acc[i][j] = zero;

    for (int k0 = 0; k0 < K; k0 += 2 * BKT) {
        // ---- even half: buffer 0 ----
#pragma unroll
        for (int i = 0; i < NA; i++)
            *(short8*)&As[0][(r0 + 64 * i) * LDA + c0] = sa0[i];
#pragma unroll
        for (int i = 0; i < NB; i++)
            *(short8*)&Bs[0][(r0 + 64 * i) * LDA + c0] = sb0[i];
        __syncthreads();
        if (k0 + 2 * BKT < K) ldg(k0 + 2 * BKT, sa0, sb0);
        {
            short8 af[FM], bf[FN];
#pragma unroll
            for (int i = 0; i < FM; i++)
                af[i] = *(const short8*)&As[0][(wr * FM * 16 + i * 16 + l16) * LDA + quad * 8];
#pragma unroll
            for (int j = 0; j < FN; j++)
                bf[j] = *(const short8*)&Bs[0][(wc * FN * 16 + j * 16 + l16) * LDA + quad * 8];
#pragma unroll
            for (int i = 0; i < FM; i++)
#pragma unroll
                for (int j = 0; j < FN; j++)
                    acc[i][j] = __builtin_amdgcn_mfma_f32_16x16x32_bf16(
                        af[i], bf[j], acc[i][j], 0, 0, 0);
        }
        // ---- odd half: buffer 1 ----
#pragma unroll
        for (int i = 0; i < NA; i++)
            *(short8*)&As[1][(r0 + 64 * i) * LDA + c0] = sa1[i];
#pragma unroll
        for (int i = 0; i < NB; i++)
            *(short8*)&Bs[1][(r0 + 64 * i) * LDA + c0] = sb1[i];
        __syncthreads();
        if (k0 + 3 * BKT < K) ldg(k0 + 3 * BKT, sa1, sb1);
        {
            short8 af[FM], bf[FN];
#pragma unroll
            for (int i = 0; i < FM; i++)
                af[i] = *(const short8*)&As[1][(wr * FM * 16 + i * 16 + l16) * LDA + quad * 8];
#pragma unroll
            for (int j = 0; j < FN; j++)
                bf[j] = *(const short8*)&Bs[1][(wc * FN * 16 + j * 16 + l16) * LDA + quad * 8];
#pragma unroll
            for (int i = 0; i < FM; i++)
#pragma unroll
                for (int j = 0; j < FN; j++)
                    acc[i][j] = __builtin_amdgcn_mfma_f32_16x16x32_bf16(
                        af[i], bf[j], acc[i][j], 0, 0, 0);
        }
    }

    if constexpr (EPI == 5) {
        int colbase = n0 + wc * FN * 16;           // 64-aligned => one head per wave
        int portion = colbase >> 10;               // 0=q 1=k 2=v
        int hh = (colbase >> 6) & 15;
        float bv[FN];
#pragma unroll
        for (int j = 0; j < FN; j++) bv[j] = bias[colbase + j * 16 + l16];
        if (portion == 2) {
#pragma unroll
            for (int i = 0; i < FM; i++)
#pragma unroll
                for (int j = 0; j < FN; j++)
#pragma unroll
                    for (int r = 0; r < 4; r++) {
                        int row = m0 + wr * FM * 16 + i * 16 + quad * 4 + r;
                        int bb = row >> 10, nn = row & 1023;
                        int dd = j * 16 + l16;
                        b0[((size_t)(bb * 16 + hh) * DHEAD + dd) * NSEQ + nn] =
                            __float2bfloat16(acc[i][j][r] + bv[j]);
                    }
        } else {
            const float* g  = (portion == 0) ? g0 : g1;
            const float* be = (portion == 0) ? be0 : be1;
            __hip_bfloat16* dst = (portion == 0) ? b1 : b2;
            float gv[FN], bev[FN];
#pragma unroll
            for (int j = 0; j < FN; j++) {
                gv[j] = g[j * 16 + l16];
                bev[j] = be[j * 16 + l16];
            }
#pragma unroll
            for (int i = 0; i < FM; i++)
#pragma unroll
                for (int r = 0; r < 4; r++) {
                    float s1 = 0.f, s2 = 0.f;
#pragma unroll
                    for (int j = 0; j < FN; j++) {
                        float v = acc[i][j][r] + bv[j];
                        s1 += v; s2 += v * v;
                    }
#pragma unroll
                    for (int mk = 1; mk < 16; mk <<= 1) {
                        s1 += __shfl_xor(s1, mk, 64);
                        s2 += __shfl_xor(s2, mk, 64);
                    }
                    float mean = s1 * (1.f / 64.f);
                    float var = s2 * (1.f / 64.f) - mean * mean;
                    float rs = rsqrtf(var + 1e-5f);
                    int row = m0 + wr * FM * 16 + i * 16 + quad * 4 + r;
                    int bb = row >> 10, nn = row & 1023;
                    size_t base = ((size_t)(bb * 16 + hh) * NSEQ + nn) * DHEAD;
#pragma unroll
                    for (int j = 0; j < FN; j++)
                        dst[base + j * 16 + l16] = __float2bfloat16(
                            (acc[i][j][r] + bv[j] - mean) * rs * gv[j] + bev[j]);
                }
        }
        return;
    }

    float wmx = 0.f, w0c = 0.f, w14c = 0.f;
    if (EPI == 1) {
        wmx = softw(wvec, 2);
        w0c = softw(wvec, 0);
        w14c = softw(wvec, 1) + softw(wvec, 4);
    }
    if (EPI == 3) wmx = softw(wvec, 5);

#pragma unroll
    for (int i = 0; i < FM; i++) {
#pragma unroll
        for (int j = 0; j < FN; j++) {
            int col = n0 + wc * FN * 16 + j * 16 + l16;
            float bv = bias[col];
#pragma unroll
            for (int r = 0; r < 4; r++) {
                int row = m0 + wr * FM * 16 + i * 16 + quad * 4 + r;
                float v = acc[i][j][r] + bv;
                size_t idx = (size_t)row * N + col;
                if (EPI == 1) {
                    float2 xl = *((const float2*)f1 + idx);   // x_list pair
                    f0[idx] = w0c * xl.x + w14c * xl.y + wmx * gelu_f(v);
                } else if (EPI == 2) {
                    b0[idx] = __float2bfloat16(gelu_f(v));    // mlp hidden
                } else if (EPI == 3) {
                    float tv = f0[idx] + wmx * v;             // final mix
                    f0[idx] = tv;
                    b0[idx] = __float2bfloat16(tv);
                } else if (EPI == 4) {
                    f0[idx] = v + f1[idx];                    // proj + residual
                }
            }
        }
    }
}

// ---------- ca1: h1 = relu(x @ ca1_w^T + b)  [4096,64], K=1024, x bf16 ----------
__global__ __launch_bounds__(256) void ca1_kernel(
    const __hip_bfloat16* __restrict__ xb, const float* __restrict__ w,
    const float* __restrict__ bias, float* __restrict__ h1)
{
    __shared__ float Xs[16 * 65];
    __shared__ float Ws[64 * 65];
    int t = threadIdx.x;
    int m0 = blockIdx.x * 16;
    int row = t >> 4, cg = t & 15;
    float acc[4] = {0.f, 0.f, 0.f, 0.f};
    for (int k0 = 0; k0 < 1024; k0 += 64) {
#pragma unroll
        for (int i = 0; i < 4; i++) {
            int e = t + i * 256; int r = e >> 6, c = e & 63;
            Xs[r * 65 + c] = __bfloat162float(xb[(size_t)(m0 + r) * 1024 + k0 + c]);
        }
#pragma unroll
        for (int i = 0; i < 16; i++) {
            int e = t + i * 256; int r = e >> 6, c = e & 63;
            Ws[r * 65 + c] = w[(size_t)r * 1024 + k0 + c];
        }
        __syncthreads();
        for (int k = 0; k < 64; k++) {
            float xv = Xs[row * 65 + k];
#pragma unroll
            for (int c = 0; c < 4; c++)
                acc[c] += xv * Ws[(cg * 4 + c) * 65 + k];
        }
        __syncthreads();
    }
#pragma unroll
    for (int c = 0; c < 4; c++)
        h1[(size_t)(m0 + row) * 64 + cg * 4 + c] =
            fmaxf(acc[c] + bias[cg * 4 + c], 0.f);
}

// ---------- ca2: xmix += w3 * sigmoid(h1 @ ca2_w^T + b) * x ----------
__global__ __launch_bounds__(256) void ca2_kernel(
    const float* __restrict__ h1, const float* __restrict__ w,
    const float* __restrict__ bias, const __hip_bfloat16* __restrict__ xb,
    float* __restrict__ xmix, const float* __restrict__ wvec)
{
    __shared__ float Wt[256 * 65];
    __shared__ float hs[16 * 64];
    int t = threadIdx.x;
    int m0 = blockIdx.x * 16, n0 = blockIdx.y * 256;
#pragma unroll
    for (int i = 0; i < 64; i++) {
        int e = t + i * 256; int r = e >> 6, c = e & 63;
        Wt[r * 65 + c] = w[(size_t)(n0 + r) * 64 + c];
    }
#pragma unroll
    for (int i = 0; i < 4; i++) {
        int e = t + i * 256; int r = e >> 6, c = e & 63;
        hs[r * 64 + c] = h1[(size_t)(m0 + r) * 64 + c];
    }
    __syncthreads();
    int n = n0 + t;
    float bv = bias[n];
    float acc[16];
#pragma unroll
    for (int mi = 0; mi < 16; mi++) acc[mi] = bv;
    for (int k = 0; k < 64; k++) {
        float wv = Wt[t * 65 + k];
#pragma unroll
        for (int mi = 0; mi < 16; mi++) acc[mi] += hs[mi * 64 + k] * wv;
    }
    float w3 = softw(wvec, 3);
#pragma unroll
    for (int mi = 0; mi < 16; mi++) {
        size_t idx = (size_t)(m0 + mi) * 1024 + n;
        float sg = 1.f / (1.f + __expf(-acc[mi]));
        xmix[idx] += w3 * sg * __bfloat162float(xb[idx]);
    }
}

// ---------- MFMA flash attention ----------
// grid (64 bh, 8 i-tiles), block 256 (4 waves). Wave owns 32 q-rows.
// Q/K bf16 [b,h,n,d]; V^T bf16 [b,h,d,n]; out ao bf16 [b,n,c].
// K/V fragments read direct from global (L2-resident per bh).
// P round-trips through wave-private LDS (no barriers in kernel).
#define PSTR 72   // bf16 stride: 144 B, 16B-aligned, 2-way banks
__global__ __launch_bounds__(256) void flash_mfma(
    const __hip_bfloat16* __restrict__ qb, const __hip_bfloat16* __restrict__ kb,
    const __hip_bfloat16* __restrict__ vt, __hip_bfloat16* __restrict__ ao)
{
    __shared__ __hip_bfloat16 Plds[4][32 * PSTR];
    int bh = blockIdx.x;
    int i0 = blockIdx.y * 128;
    int b = bh >> 4, h = bh & 15;
    int t = threadIdx.x, wave = t >> 6, lane = t & 63;
    int l16 = lane & 15, quad = lane >> 4;
    const __hip_bfloat16* qbase = qb + (size_t)bh * NSEQ * DHEAD;
    const __hip_bfloat16* kbase = kb + (size_t)bh * NSEQ * DHEAD;
    const __hip_bfloat16* vbase = vt + (size_t)bh * DHEAD * NSEQ;
    __hip_bfloat16* pw = Plds[wave];
    int qrow0 = i0 + wave * 32;

    // Q fragments, held for the whole kernel
    short8 aq[2][2];
#pragma unroll
    for (int ri = 0; ri < 2; ri++)
#pragma unroll
        for (int ks = 0; ks < 2; ks++)
            aq[ri][ks] = *(const short8*)(qbase +
                (size_t)(qrow0 + ri * 16 + l16) * DHEAD + ks * 32 + quad * 8);

    f32x4 zero = {0.f, 0.f, 0.f, 0.f};
    f32x4 o[2][4];
    float mrow[2][4], lrow[2][4];
#pragma unroll
    for (int ri = 0; ri < 2; ri++) {
#pragma unroll
        for (int nt = 0; nt < 4; nt++) o[ri][nt] = zero;
#pragma unroll
        for (int rr = 0; rr < 4; rr++) { mrow[ri][rr] = -1e30f; lrow[ri][rr] = 0.f; }
    }

    for (int j0 = 0; j0 < NSEQ; j0 += 64) {
        // K fragments: B[n=key][k=d]
        short8 bk[4][2];
#pragma unroll
        for (int jt = 0; jt < 4; jt++)
#pragma unroll
            for (int ks = 0; ks < 2; ks++)
                bk[jt][ks] = *(const short8*)(kbase +
                    (size_t)(j0 + jt * 16 + l16) * DHEAD + ks * 32 + quad * 8);
        // V^T fragments: B[n=d][k=key]
        short8 bv[4][2];
#pragma unroll
        for (int nt = 0; nt < 4; nt++)
#pragma unroll
            for (int ks = 0; ks < 2; ks++)
                bv[nt][ks] = *(const short8*)(vbase +
                    (size_t)(nt * 16 + l16) * NSEQ + j0 + ks * 32 + quad * 8);

#pragma unroll
        for (int ri = 0; ri < 2; ri++) {
            f32x4 s[4];
#pragma unroll
            for (int jt = 0; jt < 4; jt++) s[jt] = zero;
#pragma unroll
            for (int jt = 0; jt < 4; jt++)
#pragma unroll
                for (int ks = 0; ks < 2; ks++)
                    s[jt] = __builtin_amdgcn_mfma_f32_16x16x32_bf16(
                        aq[ri][ks], bk[jt][ks], s[jt], 0, 0, 0);
            // online softmax, row = quad*4+rr (C-layout), col = jt*16+l16
#pragma unroll
            for (int rr = 0; rr < 4; rr++) {
                float mx = -1e30f;
#pragma unroll
                for (int jt = 0; jt < 4; jt++) {
                    s[jt][rr] *= 0.125f;
                    mx = fmaxf(mx, s[jt][rr]);
                }
#pragma unroll
                for (int mk = 1; mk < 16; mk <<= 1) mx = fmaxf(mx, __shfl_xor(mx, mk, 64));
                float om = mrow[ri][rr];
                float nm = fmaxf(om, mx);
                float al = __expf(om - nm);
                mrow[ri][rr] = nm;
                float ss = 0.f;
#pragma unroll
                for (int jt = 0; jt < 4; jt++) {
                    float p = __expf(s[jt][rr] - nm);
                    pw[(ri * 16 + quad * 4 + rr) * PSTR + jt * 16 + l16] =
                        __float2bfloat16(p);
                    ss += p;
                }
#pragma unroll
                for (int mk = 1; mk < 16; mk <<= 1) ss += __shfl_xor(ss, mk, 64);
                lrow[ri][rr] = lrow[ri][rr] * al + ss;
#pragma unroll
                for (int nt = 0; nt < 4; nt++) o[ri][nt][rr] *= al;
            }
        }
        // PV: A = P from wave-private LDS (compiler inserts lgkmcnt wait)
#pragma unroll
        for (int ri = 0; ri < 2; ri++) {
            short8 ap[2];
#pragma unroll
            for (int ks = 0; ks < 2; ks++)
                ap[ks] = *(const short8*)&pw[(ri * 16 + l16) * PSTR + ks * 32 + quad * 8];
#pragma unroll
            for (int nt = 0; nt < 4; nt++)
#pragma unroll
                for (int ks = 0; ks < 2; ks++)
                    o[ri][nt] = __builtin_amdgcn_mfma_f32_16x16x32_bf16(
                        ap[ks], bv[nt][ks], o[ri][nt], 0, 0, 0);
        }
    }

#pragma unroll
    for (int ri = 0; ri < 2; ri++)
#pragma unroll
        for (int rr = 0; rr < 4; rr++) {
            float inv = 1.f / lrow[ri][rr];
            int row = qrow0 + ri * 16 + quad * 4 + rr;
#pragma unroll
            for (int nt = 0; nt < 4; nt++)
                ao[((size_t)b * NSEQ + row) * CDIM + h * 64 + nt * 16 + l16] =
                    __float2bfloat16(o[ri][nt][rr] * inv);
        }
}

// ---------- attn_map: mean over heads of attn[:,0,1:] ----------
__global__ __launch_bounds__(256) void attn_map_acc(
    const __hip_bfloat16* __restrict__ qf, const __hip_bfloat16* __restrict__ kf,
    float* __restrict__ am)
{
    __shared__ float q0[64];
    __shared__ float red[256];
    int bh = blockIdx.x, t = threadIdx.x;
    const __hip_bfloat16* qr = qf + (size_t)bh * NSEQ * DHEAD;   // row 0
    const __hip_bfloat16* kb = kf + (size_t)bh * NSEQ * DHEAD;
    if (t < 64) q0[t] = __bfloat162float(qr[t]);
    __syncthreads();
    float s[4];
    float mx = -1e30f;
#pragma unroll
    for (int ji = 0; ji < 4; ji++) {
        int j = ji * 256 + t;
        float a = 0.f;
        for (int k = 0; k < 64; k++) a += q0[k] * __bfloat162float(kb[(size_t)j * 64 + k]);
        a *= 0.125f;
        s[ji] = a;
        mx = fmaxf(mx, a);
    }
    red[t] = mx; __syncthreads();
    for (int st = 128; st > 0; st >>= 1) {
        if (t < st) red[t] = fmaxf(red[t], red[t + st]);
        __syncthreads();
    }
    float M = red[0]; __syncthreads();
    float sum = 0.f;
#pragma unroll
    for (int ji = 0; ji < 4; ji++) { s[ji] = __expf(s[ji] - M); sum += s[ji]; }
    red[t] = sum; __syncthreads();
    for (int st = 128; st > 0; st >>= 1) {
        if (t < st) red[t] += red[t + st];
        __syncthreads();
    }
    float inv = 1.f / red[0];
    int b = bh >> 4;
#pragma unroll
    for (int ji = 0; ji < 4; ji++) {
        int j = ji * 256 + t;
        if (j > 0) atomicAdd(&am[b * 1024 + j], s[ji] * inv * (1.f / 16.f));
    }
}

__global__ __launch_bounds__(256) void attn_map_out(
    const float* __restrict__ am, float* __restrict__ out1)
{
    int i = blockIdx.x * 256 + threadIdx.x;
    if (i < 4 * 1023) {
        int b = i / 1023;
        int j = i - b * 1023 + 1;
        out1[i] = am[b * 1024 + j];
    }
}

// ---------- launch ----------
extern "C" void kernel_launch(void* const* d_in, const int* in_sizes, int n_in,
                              void* d_out, int out_size, void* d_ws, size_t ws_size,
                              hipStream_t stream)
{
    const float* x_list = (const float*)d_in[0];
    const float* wvec   = (const float*)d_in[1];
    const float* qkv_w  = (const float*)d_in[2];
    const float* qkv_b  = (const float*)d_in[3];
    const float* proj_w = (const float*)d_in[4];
    const float* proj_b = (const float*)d_in[5];
    const float* nq_g   = (const float*)d_in[6];
    const float* nq_b   = (const float*)d_in[7];
    const float* nk_g   = (const float*)d_in[8];
    const float* nk_b   = (const float*)d_in[9];
    const float* conv_w = (const float*)d_in[10];
    const float* conv_b = (const float*)d_in[11];
    const float* ca1_w  = (const float*)d_in[12];
    const float* ca1_b  = (const float*)d_in[13];
    const float* ca2_w  = (const float*)d_in[14];
    const float* ca2_b  = (const float*)d_in[15];
    const float* mlp1_w = (const float*)d_in[16];
    const float* mlp1_b = (const float*)d_in[17];
    const float* mlp2_w = (const float*)d_in[18];
    const float* mlp2_b = (const float*)d_in[19];

    float* out0 = (float*)d_out;
    float* out1 = out0 + (size_t)4 * 1024 * 1024;

    char* ws = (char*)d_ws;
    size_t off = 0;
    auto alloc = [&](size_t bytes) -> char* {
        char* p = ws + off;
        off += (bytes + 255) & ~(size_t)255;
        return p;
    };
    __hip_bfloat16* xb     = (__hip_bfloat16*)alloc((size_t)MROWS * CDIM * 2);
    float*          xmix   = (float*)alloc((size_t)MROWS * CDIM * 4);
    __hip_bfloat16* xmixb  = (__hip_bfloat16*)alloc((size_t)MROWS * CDIM * 2);
    float*          h1     = (float*)alloc((size_t)MROWS * 64 * 4);
    __hip_bfloat16* hb     = (__hip_bfloat16*)alloc((size_t)MROWS * 4096 * 2);
    __hip_bfloat16* qbb    = (__hip_bfloat16*)alloc((size_t)MROWS * CDIM * 2);
    __hip_bfloat16* kbb    = (__hip_bfloat16*)alloc((size_t)MROWS * CDIM * 2);
    __hip_bfloat16* vtb    = (__hip_bfloat16*)alloc((size_t)MROWS * CDIM * 2);
    __hip_bfloat16* aob    = (__hip_bfloat16*)alloc((size_t)MROWS * CDIM * 2);
    float*          amacc  = (float*)alloc(4096 * 4);
    __hip_bfloat16* convwb = (__hip_bfloat16*)alloc((size_t)1048576 * 2);
    __hip_bfloat16* qkvwb  = (__hip_bfloat16*)alloc((size_t)3145728 * 2);
    __hip_bfloat16* projwb = (__hip_bfloat16*)alloc((size_t)1048576 * 2);
    __hip_bfloat16* mlp1wb = (__hip_bfloat16*)alloc((size_t)4194304 * 2);
    __hip_bfloat16* mlp2wb = (__hip_bfloat16*)alloc((size_t)4194304 * 2);

    // weight converts
    f2b<<<4096, 256, 0, stream>>>(conv_w, convwb, 1048576);
    f2b<<<12288, 256, 0, stream>>>(qkv_w, qkvwb, 3145728);
    f2b<<<4096, 256, 0, stream>>>(proj_w, projwb, 1048576);
    f2b<<<16384, 256, 0, stream>>>(mlp1_w, mlp1wb, 4194304);
    f2b<<<16384, 256, 0, stream>>>(mlp2_w, mlp2wb, 4194304);

    // prologue: x -> bf16 only
    mix_base<<<16384, 256, 0, stream>>>(x_list, xb, amacc);

    // op0: conv (gelu) epilogue also writes base mix from x_list
    gemm_bf16<1, 4, 2><<<dim3(16, 32), 256, 0, stream>>>(
        xb, convwb, conv_b, xmix, (float*)x_list, nullptr, nullptr, nullptr,
        nullptr, nullptr, nullptr, nullptr, wvec, MROWS, 1024, 1024);

    // op1: channel attention (must follow conv's xmix write)
    ca1_kernel<<<256, 256, 0, stream>>>(xb, ca1_w, ca1_b, h1);
    ca2_kernel<<<dim3(256, 4), 256, 0, stream>>>(h1, ca2_w, ca2_b, xb, xmix, wvec);

    // op3: MLP
    gemm_bf16<2, 4, 4><<<dim3(32, 32), 256, 0, stream>>>(
        xb, mlp1wb, mlp1_b, nullptr, nullptr, hb, nullptr, nullptr,
        nullptr, nullptr, nullptr, nullptr, wvec, MROWS, 4096, 1024);
    gemm_bf16<3, 4, 2><<<dim3(16, 32), 256, 0, stream>>>(
        hb, mlp2wb, mlp2_b, xmix, nullptr, xmixb, nullptr, nullptr,
        nullptr, nullptr, nullptr, nullptr, wvec, MROWS, 1024, 4096);

    // qkv with fused per-head LN: q->qbb, k->kbb bf16 [b,h,n,d]; v->V^T bf16
    gemm_bf16<5, 4, 4><<<dim3(24, 32), 256, 0, stream>>>(
        xmixb, qkvwb, qkv_b, nullptr, nullptr, vtb, qbb, kbb,
        nq_g, nq_b, nk_g, nk_b, wvec, MROWS, 3072, 1024);

    // attention (MFMA)
    flash_mfma<<<dim3(64, 8), 256, 0, stream>>>(qbb, kbb, vtb, aob);

    // attn_map
    attn_map_acc<<<64, 256, 0, stream>>>(qbb, kbb, amacc);
    attn_map_out<<<16, 256, 0, stream>>>(amacc, out1);

    // projection + residual
    gemm_bf16<4, 4, 2><<<dim3(16, 32), 256, 0, stream>>>(
        aob, projwb, proj_b, out0, xmix, nullptr, nullptr, nullptr,
        nullptr, nullptr, nullptr, nullptr, wvec, MROWS, 1024, 1024);
}

// Round 7
// 548.429 us; speedup vs baseline: 9.1182x; 1.0007x over previous
//
#include <hip/hip_runtime.h>
#include <hip/hip_bf16.h>

// ---------- types ----------
typedef __attribute__((ext_vector_type(8))) short short8;
typedef __attribute__((ext_vector_type(4))) float f32x4;

#define MROWS 4096      // b*l
#define CDIM  1024
#define HEADS 16
#define DHEAD 64
#define NSEQ  1024

// ---------- small device helpers ----------
__device__ inline float softw(const float* __restrict__ w, int idx) {
    // softmax(w/0.01)[idx] over 6 entries
    float m = w[0];
#pragma unroll
    for (int i = 1; i < 6; i++) m = fmaxf(m, w[i]);
    float s = 0.f, v = 0.f;
#pragma unroll
    for (int i = 0; i < 6; i++) {
        float e = __expf((w[i] - m) * 100.0f);
        s += e;
        if (i == idx) v = e;
    }
    return v / s;
}

__device__ inline float gelu_f(float x) {
    return 0.5f * x * (1.0f + erff(x * 0.70710678118654752f));
}

// ---------- prologue: x -> bf16, zero attn-map accumulator ----------
__global__ __launch_bounds__(256) void mix_base(
    const float* __restrict__ x_list, __hip_bfloat16* __restrict__ xb,
    float* __restrict__ am_acc)
{
    int i = blockIdx.x * 256 + threadIdx.x;   // 0 .. 4M-1
    xb[i] = __float2bfloat16(x_list[2 * (size_t)i + 1]);
    if (i < 4096) am_acc[i] = 0.f;
}

// ---------- fp32 -> bf16 weight convert ----------
__global__ __launch_bounds__(256) void f2b(const float* __restrict__ in,
                                           __hip_bfloat16* __restrict__ out, int n)
{
    int i = blockIdx.x * 256 + threadIdx.x;
    if (i < n) out[i] = __float2bfloat16(in[i]);
}

// ---------- bf16 MFMA GEMM, dbuf LDS + depth-2 register prefetch ----------
// Manually 2x-unrolled K-loop: ALL private arrays statically indexed
// (dynamic indices spill staging to scratch: 28x slower, round 5).
// grid.x = n-tiles so block->XCD round-robin pins B-tiles in per-XCD L2.
// EPI: 1=fused conv+mlp1 (col<1024: base mix from x_list + w2*gelu -> xmixb bf16;
//                         col>=1024: gelu -> hb bf16)
//      3=mlp2 (xmixb += w5*v, bf16 rmw), 4=proj (+bias+residual(bf16) -> f0 f32),
//      5=qkv (fused per-head LN: q->b1, k->b2 bf16 [b,h,n,d]; v->b0 V^T bf16)
#define BKT 32
#define LDA 40   // 32 + 8 pad (16B aligned, 2-way LDS banks = free)

template<int EPI, int FM, int FN>
__global__ __launch_bounds__(256) void gemm_bf16(
    const __hip_bfloat16* __restrict__ A, const __hip_bfloat16* __restrict__ W,
    const float* __restrict__ bias,
    float* __restrict__ f0, const float* __restrict__ f1,
    __hip_bfloat16* __restrict__ b0, __hip_bfloat16* __restrict__ b1,
    __hip_bfloat16* __restrict__ b2,
    const float* __restrict__ g0, const float* __restrict__ be0,
    const float* __restrict__ g1, const float* __restrict__ be1,
    const float* __restrict__ wvec, int M, int N, int K)
{
    constexpr int BMt = FM * 32;
    constexpr int BNt = FN * 32;
    constexpr int NA = BMt / 64;    // short8 staged per thread (A)
    constexpr int NB = BNt / 64;    // short8 staged per thread (B)
    __shared__ __hip_bfloat16 As[2][BMt * LDA];
    __shared__ __hip_bfloat16 Bs[2][BNt * LDA];
    int t = threadIdx.x;
    int n0 = blockIdx.x * BNt, m0 = blockIdx.y * BMt;
    int wave = t >> 6, lane = t & 63;
    int wr = wave >> 1, wc = wave & 1;
    int quad = lane >> 4, l16 = lane & 15;
    int r0 = t >> 2, c0 = (t & 3) * 8;    // staging: 4 lanes/row, 64 rows/round

    short8 sa0[NA], sb0[NB], sa1[NA], sb1[NB];
    auto ldg = [&](int k0, short8* da, short8* db) {
#pragma unroll
        for (int i = 0; i < NA; i++)
            da[i] = *(const short8*)(A + (size_t)(m0 + r0 + 64 * i) * K + k0 + c0);
#pragma unroll
        for (int i = 0; i < NB; i++)
            db[i] = *(const short8*)(W + (size_t)(n0 + r0 + 64 * i) * K + k0 + c0);
    };
    ldg(0, sa0, sb0);
    ldg(BKT, sa1, sb1);

    f32x4 zero = {0.f, 0.f, 0.f, 0.f};
    f32x4 acc[FM][FN];
#pragma unroll
    for (int i = 0; i < FM; i++)
#pragma unroll
        for (int j = 0; j < FN; j++) acc[i][j] = zero;

    for (int k0 = 0; k0 < K; k0 += 2 * BKT) {
        // ---- even half: buffer 0 ----
#pragma unroll
        for (int i = 0; i < NA; i++)
            *(short8*)&As[0][(r0 + 64 * i) * LDA + c0] = sa0[i];
#pragma unroll
        for (int i = 0; i < NB; i++)
            *(short8*)&Bs[0][(r0 + 64 * i) * LDA + c0] = sb0[i];
        __syncthreads();
        if (k0 + 2 * BKT < K) ldg(k0 + 2 * BKT, sa0, sb0);
        {
            short8 af[FM], bf[FN];
#pragma unroll
            for (int i = 0; i < FM; i++)
                af[i] = *(const short8*)&As[0][(wr * FM * 16 + i * 16 + l16) * LDA + quad * 8];
#pragma unroll
            for (int j = 0; j < FN; j++)
                bf[j] = *(const short8*)&Bs[0][(wc * FN * 16 + j * 16 + l16) * LDA + quad * 8];
#pragma unroll
            for (int i = 0; i < FM; i++)
#pragma unroll
                for (int j = 0; j < FN; j++)
                    acc[i][j] = __builtin_amdgcn_mfma_f32_16x16x32_bf16(
                        af[i], bf[j], acc[i][j], 0, 0, 0);
        }
        // ---- odd half: buffer 1 ----
#pragma unroll
        for (int i = 0; i < NA; i++)
            *(short8*)&As[1][(r0 + 64 * i) * LDA + c0] = sa1[i];
#pragma unroll
        for (int i = 0; i < NB; i++)
            *(short8*)&Bs[1][(r0 + 64 * i) * LDA + c0] = sb1[i];
        __syncthreads();
        if (k0 + 3 * BKT < K) ldg(k0 + 3 * BKT, sa1, sb1);
        {
            short8 af[FM], bf[FN];
#pragma unroll
            for (int i = 0; i < FM; i++)
                af[i] = *(const short8*)&As[1][(wr * FM * 16 + i * 16 + l16) * LDA + quad * 8];
#pragma unroll
            for (int j = 0; j < FN; j++)
                bf[j] = *(const short8*)&Bs[1][(wc * FN * 16 + j * 16 + l16) * LDA + quad * 8];
#pragma unroll
            for (int i = 0; i < FM; i++)
#pragma unroll
                for (int j = 0; j < FN; j++)
                    acc[i][j] = __builtin_amdgcn_mfma_f32_16x16x32_bf16(
                        af[i], bf[j], acc[i][j], 0, 0, 0);
        }
    }

    if constexpr (EPI == 1) {
        // fused conv (cols 0..1023) + mlp1 (cols 1024..5119). 64-col wave span
        // never straddles the boundary (1024 % 64 == 0) -> wave-uniform branch.
        float wmx = softw(wvec, 2);
        float w0c = softw(wvec, 0);
        float w14c = softw(wvec, 1) + softw(wvec, 4);
        int colbase = n0 + wc * FN * 16;
        bool isconv = colbase < 1024;
#pragma unroll
        for (int i = 0; i < FM; i++) {
#pragma unroll
            for (int j = 0; j < FN; j++) {
                int col = colbase + j * 16 + l16;
                float bv = isconv ? bias[col] : be0[col - 1024];
#pragma unroll
                for (int r = 0; r < 4; r++) {
                    int row = m0 + wr * FM * 16 + i * 16 + quad * 4 + r;
                    float v = acc[i][j][r] + bv;
                    if (isconv) {
                        size_t idx = (size_t)row * 1024 + col;
                        float2 xl = ((const float2*)f1)[idx];
                        b0[idx] = __float2bfloat16(
                            w0c * xl.x + w14c * xl.y + wmx * gelu_f(v));
                    } else {
                        b1[(size_t)row * 4096 + (col - 1024)] =
                            __float2bfloat16(gelu_f(v));
                    }
                }
            }
        }
        return;
    }

    if constexpr (EPI == 5) {
        int colbase = n0 + wc * FN * 16;           // 64-aligned => one head per wave
        int portion = colbase >> 10;               // 0=q 1=k 2=v
        int hh = (colbase >> 6) & 15;
        float bv[FN];
#pragma unroll
        for (int j = 0; j < FN; j++) bv[j] = bias[colbase + j * 16 + l16];
        if (portion == 2) {
#pragma unroll
            for (int i = 0; i < FM; i++)
#pragma unroll
                for (int j = 0; j < FN; j++)
#pragma unroll
                    for (int r = 0; r < 4; r++) {
                        int row = m0 + wr * FM * 16 + i * 16 + quad * 4 + r;
                        int bb = row >> 10, nn = row & 1023;
                        int dd = j * 16 + l16;
                        b0[((size_t)(bb * 16 + hh) * DHEAD + dd) * NSEQ + nn] =
                            __float2bfloat16(acc[i][j][r] + bv[j]);
                    }
        } else {
            const float* g  = (portion == 0) ? g0 : g1;
            const float* be = (portion == 0) ? be0 : be1;
            __hip_bfloat16* dst = (portion == 0) ? b1 : b2;
            float gv[FN], bev[FN];
#pragma unroll
            for (int j = 0; j < FN; j++) {
                gv[j] = g[j * 16 + l16];
                bev[j] = be[j * 16 + l16];
            }
#pragma unroll
            for (int i = 0; i < FM; i++)
#pragma unroll
                for (int r = 0; r < 4; r++) {
                    float s1 = 0.f, s2 = 0.f;
#pragma unroll
                    for (int j = 0; j < FN; j++) {
                        float v = acc[i][j][r] + bv[j];
                        s1 += v; s2 += v * v;
                    }
#pragma unroll
                    for (int mk = 1; mk < 16; mk <<= 1) {
                        s1 += __shfl_xor(s1, mk, 64);
                        s2 += __shfl_xor(s2, mk, 64);
                    }
                    float mean = s1 * (1.f / 64.f);
                    float var = s2 * (1.f / 64.f) - mean * mean;
                    float rs = rsqrtf(var + 1e-5f);
                    int row = m0 + wr * FM * 16 + i * 16 + quad * 4 + r;
                    int bb = row >> 10, nn = row & 1023;
                    size_t base = ((size_t)(bb * 16 + hh) * NSEQ + nn) * DHEAD;
#pragma unroll
                    for (int j = 0; j < FN; j++)
                        dst[base + j * 16 + l16] = __float2bfloat16(
                            (acc[i][j][r] + bv[j] - mean) * rs * gv[j] + bev[j]);
                }
        }
        return;
    }

    float wmx = 0.f;
    if (EPI == 3) wmx = softw(wvec, 5);

#pragma unroll
    for (int i = 0; i < FM; i++) {
#pragma unroll
        for (int j = 0; j < FN; j++) {
            int col = n0 + wc * FN * 16 + j * 16 + l16;
            float bv = bias[col];
#pragma unroll
            for (int r = 0; r < 4; r++) {
                int row = m0 + wr * FM * 16 + i * 16 + quad * 4 + r;
                float v = acc[i][j][r] + bv;
                size_t idx = (size_t)row * N + col;
                if (EPI == 3) {
                    // final mix: xmixb += w5 * v (bf16 rmw)
                    float tv = __bfloat162float(b0[idx]) + wmx * v;
                    b0[idx] = __float2bfloat16(tv);
                } else if (EPI == 4) {
                    f0[idx] = v + __bfloat162float(b1[idx]);  // proj + residual
                }
            }
        }
    }
}

// ---------- ca1: h1 = relu(x @ ca1_w^T + b)  [4096,64], K=1024, x bf16 ----------
__global__ __launch_bounds__(256) void ca1_kernel(
    const __hip_bfloat16* __restrict__ xb, const float* __restrict__ w,
    const float* __restrict__ bias, float* __restrict__ h1)
{
    __shared__ float Xs[16 * 65];
    __shared__ float Ws[64 * 65];
    int t = threadIdx.x;
    int m0 = blockIdx.x * 16;
    int row = t >> 4, cg = t & 15;
    float acc[4] = {0.f, 0.f, 0.f, 0.f};
    for (int k0 = 0; k0 < 1024; k0 += 64) {
#pragma unroll
        for (int i = 0; i < 4; i++) {
            int e = t + i * 256; int r = e >> 6, c = e & 63;
            Xs[r * 65 + c] = __bfloat162float(xb[(size_t)(m0 + r) * 1024 + k0 + c]);
        }
#pragma unroll
        for (int i = 0; i < 16; i++) {
            int e = t + i * 256; int r = e >> 6, c = e & 63;
            Ws[r * 65 + c] = w[(size_t)r * 1024 + k0 + c];
        }
        __syncthreads();
        for (int k = 0; k < 64; k++) {
            float xv = Xs[row * 65 + k];
#pragma unroll
            for (int c = 0; c < 4; c++)
                acc[c] += xv * Ws[(cg * 4 + c) * 65 + k];
        }
        __syncthreads();
    }
#pragma unroll
    for (int c = 0; c < 4; c++)
        h1[(size_t)(m0 + row) * 64 + cg * 4 + c] =
            fmaxf(acc[c] + bias[cg * 4 + c], 0.f);
}

// ---------- ca2: xmixb += w3 * sigmoid(h1 @ ca2_w^T + b) * x  (bf16 rmw) ----------
__global__ __launch_bounds__(256) void ca2_kernel(
    const float* __restrict__ h1, const float* __restrict__ w,
    const float* __restrict__ bias, const __hip_bfloat16* __restrict__ xb,
    __hip_bfloat16* __restrict__ xmixb, const float* __restrict__ wvec)
{
    __shared__ float Wt[256 * 65];
    __shared__ float hs[16 * 64];
    int t = threadIdx.x;
    int m0 = blockIdx.x * 16, n0 = blockIdx.y * 256;
#pragma unroll
    for (int i = 0; i < 64; i++) {
        int e = t + i * 256; int r = e >> 6, c = e & 63;
        Wt[r * 65 + c] = w[(size_t)(n0 + r) * 64 + c];
    }
#pragma unroll
    for (int i = 0; i < 4; i++) {
        int e = t + i * 256; int r = e >> 6, c = e & 63;
        hs[r * 64 + c] = h1[(size_t)(m0 + r) * 64 + c];
    }
    __syncthreads();
    int n = n0 + t;
    float bv = bias[n];
    float acc[16];
#pragma unroll
    for (int mi = 0; mi < 16; mi++) acc[mi] = bv;
    for (int k = 0; k < 64; k++) {
        float wv = Wt[t * 65 + k];
#pragma unroll
        for (int mi = 0; mi < 16; mi++) acc[mi] += hs[mi * 64 + k] * wv;
    }
    float w3 = softw(wvec, 3);
#pragma unroll
    for (int mi = 0; mi < 16; mi++) {
        size_t idx = (size_t)(m0 + mi) * 1024 + n;
        float sg = 1.f / (1.f + __expf(-acc[mi]));
        float cur = __bfloat162float(xmixb[idx]);
        xmixb[idx] = __float2bfloat16(cur + w3 * sg * __bfloat162float(xb[idx]));
    }
}

// ---------- MFMA flash attention ----------
// grid (64 bh, 8 i-tiles), block 256 (4 waves). Wave owns 32 q-rows.
// Q/K bf16 [b,h,n,d]; V^T bf16 [b,h,d,n]; out ao bf16 [b,n,c].
// K/V fragments read direct from global (L2-resident per bh).
// P round-trips through wave-private LDS (no barriers in kernel).
#define PSTR 72   // bf16 stride: 144 B, 16B-aligned, 2-way banks
__global__ __launch_bounds__(256) void flash_mfma(
    const __hip_bfloat16* __restrict__ qb, const __hip_bfloat16* __restrict__ kb,
    const __hip_bfloat16* __restrict__ vt, __hip_bfloat16* __restrict__ ao)
{
    __shared__ __hip_bfloat16 Plds[4][32 * PSTR];
    int bh = blockIdx.x;
    int i0 = blockIdx.y * 128;
    int b = bh >> 4, h = bh & 15;
    int t = threadIdx.x, wave = t >> 6, lane = t & 63;
    int l16 = lane & 15, quad = lane >> 4;
    const __hip_bfloat16* qbase = qb + (size_t)bh * NSEQ * DHEAD;
    const __hip_bfloat16* kbase = kb + (size_t)bh * NSEQ * DHEAD;
    const __hip_bfloat16* vbase = vt + (size_t)bh * DHEAD * NSEQ;
    __hip_bfloat16* pw = Plds[wave];
    int qrow0 = i0 + wave * 32;

    // Q fragments, held for the whole kernel
    short8 aq[2][2];
#pragma unroll
    for (int ri = 0; ri < 2; ri++)
#pragma unroll
        for (int ks = 0; ks < 2; ks++)
            aq[ri][ks] = *(const short8*)(qbase +
                (size_t)(qrow0 + ri * 16 + l16) * DHEAD + ks * 32 + quad * 8);

    f32x4 zero = {0.f, 0.f, 0.f, 0.f};
    f32x4 o[2][4];
    float mrow[2][4], lrow[2][4];
#pragma unroll
    for (int ri = 0; ri < 2; ri++) {
#pragma unroll
        for (int nt = 0; nt < 4; nt++) o[ri][nt] = zero;
#pragma unroll
        for (int rr = 0; rr < 4; rr++) { mrow[ri][rr] = -1e30f; lrow[ri][rr] = 0.f; }
    }

    for (int j0 = 0; j0 < NSEQ; j0 += 64) {
        // K fragments: B[n=key][k=d]
        short8 bk[4][2];
#pragma unroll
        for (int jt = 0; jt < 4; jt++)
#pragma unroll
            for (int ks = 0; ks < 2; ks++)
                bk[jt][ks] = *(const short8*)(kbase +
                    (size_t)(j0 + jt * 16 + l16) * DHEAD + ks * 32 + quad * 8);
        // V^T fragments: B[n=d][k=key]
        short8 bv[4][2];
#pragma unroll
        for (int nt = 0; nt < 4; nt++)
#pragma unroll
            for (int ks = 0; ks < 2; ks++)
                bv[nt][ks] = *(const short8*)(vbase +
                    (size_t)(nt * 16 + l16) * NSEQ + j0 + ks * 32 + quad * 8);

#pragma unroll
        for (int ri = 0; ri < 2; ri++) {
            f32x4 s[4];
#pragma unroll
            for (int jt = 0; jt < 4; jt++) s[jt] = zero;
#pragma unroll
            for (int jt = 0; jt < 4; jt++)
#pragma unroll
                for (int ks = 0; ks < 2; ks++)
                    s[jt] = __builtin_amdgcn_mfma_f32_16x16x32_bf16(
                        aq[ri][ks], bk[jt][ks], s[jt], 0, 0, 0);
            // online softmax, row = quad*4+rr (C-layout), col = jt*16+l16
#pragma unroll
            for (int rr = 0; rr < 4; rr++) {
                float mx = -1e30f;
#pragma unroll
                for (int jt = 0; jt < 4; jt++) {
                    s[jt][rr] *= 0.125f;
                    mx = fmaxf(mx, s[jt][rr]);
                }
#pragma unroll
                for (int mk = 1; mk < 16; mk <<= 1) mx = fmaxf(mx, __shfl_xor(mx, mk, 64));
                float om = mrow[ri][rr];
                float nm = fmaxf(om, mx);
                float al = __expf(om - nm);
                mrow[ri][rr] = nm;
                float ss = 0.f;
#pragma unroll
                for (int jt = 0; jt < 4; jt++) {
                    float p = __expf(s[jt][rr] - nm);
                    pw[(ri * 16 + quad * 4 + rr) * PSTR + jt * 16 + l16] =
                        __float2bfloat16(p);
                    ss += p;
                }
#pragma unroll
                for (int mk = 1; mk < 16; mk <<= 1) ss += __shfl_xor(ss, mk, 64);
                lrow[ri][rr] = lrow[ri][rr] * al + ss;
#pragma unroll
                for (int nt = 0; nt < 4; nt++) o[ri][nt][rr] *= al;
            }
        }
        // PV: A = P from wave-private LDS (compiler inserts lgkmcnt wait)
#pragma unroll
        for (int ri = 0; ri < 2; ri++) {
            short8 ap[2];
#pragma unroll
            for (int ks = 0; ks < 2; ks++)
                ap[ks] = *(const short8*)&pw[(ri * 16 + l16) * PSTR + ks * 32 + quad * 8];
#pragma unroll
            for (int nt = 0; nt < 4; nt++)
#pragma unroll
                for (int ks = 0; ks < 2; ks++)
                    o[ri][nt] = __builtin_amdgcn_mfma_f32_16x16x32_bf16(
                        ap[ks], bv[nt][ks], o[ri][nt], 0, 0, 0);
        }
    }

#pragma unroll
    for (int ri = 0; ri < 2; ri++)
#pragma unroll
        for (int rr = 0; rr < 4; rr++) {
            float inv = 1.f / lrow[ri][rr];
            int row = qrow0 + ri * 16 + quad * 4 + rr;
#pragma unroll
            for (int nt = 0; nt < 4; nt++)
                ao[((size_t)b * NSEQ + row) * CDIM + h * 64 + nt * 16 + l16] =
                    __float2bfloat16(o[ri][nt][rr] * inv);
        }
}

// ---------- attn_map: mean over heads of attn[:,0,1:] ----------
__global__ __launch_bounds__(256) void attn_map_acc(
    const __hip_bfloat16* __restrict__ qf, const __hip_bfloat16* __restrict__ kf,
    float* __restrict__ am)
{
    __shared__ float q0[64];
    __shared__ float red[256];
    int bh = blockIdx.x, t = threadIdx.x;
    const __hip_bfloat16* qr = qf + (size_t)bh * NSEQ * DHEAD;   // row 0
    const __hip_bfloat16* kb = kf + (size_t)bh * NSEQ * DHEAD;
    if (t < 64) q0[t] = __bfloat162float(qr[t]);
    __syncthreads();
    float s[4];
    float mx = -1e30f;
#pragma unroll
    for (int ji = 0; ji < 4; ji++) {
        int j = ji * 256 + t;
        float a = 0.f;
        for (int k = 0; k < 64; k++) a += q0[k] * __bfloat162float(kb[(size_t)j * 64 + k]);
        a *= 0.125f;
        s[ji] = a;
        mx = fmaxf(mx, a);
    }
    red[t] = mx; __syncthreads();
    for (int st = 128; st > 0; st >>= 1) {
        if (t < st) red[t] = fmaxf(red[t], red[t + st]);
        __syncthreads();
    }
    float M = red[0]; __syncthreads();
    float sum = 0.f;
#pragma unroll
    for (int ji = 0; ji < 4; ji++) { s[ji] = __expf(s[ji] - M); sum += s[ji]; }
    red[t] = sum; __syncthreads();
    for (int st = 128; st > 0; st >>= 1) {
        if (t < st) red[t] += red[t + st];
        __syncthreads();
    }
    float inv = 1.f / red[0];
    int b = bh >> 4;
#pragma unroll
    for (int ji = 0; ji < 4; ji++) {
        int j = ji * 256 + t;
        if (j > 0) atomicAdd(&am[b * 1024 + j], s[ji] * inv * (1.f / 16.f));
    }
}

__global__ __launch_bounds__(256) void attn_map_out(
    const float* __restrict__ am, float* __restrict__ out1)
{
    int i = blockIdx.x * 256 + threadIdx.x;
    if (i < 4 * 1023) {
        int b = i / 1023;
        int j = i - b * 1023 + 1;
        out1[i] = am[b * 1024 + j];
    }
}

// ---------- launch ----------
extern "C" void kernel_launch(void* const* d_in, const int* in_sizes, int n_in,
                              void* d_out, int out_size, void* d_ws, size_t ws_size,
                              hipStream_t stream)
{
    const float* x_list = (const float*)d_in[0];
    const float* wvec   = (const float*)d_in[1];
    const float* qkv_w  = (const float*)d_in[2];
    const float* qkv_b  = (const float*)d_in[3];
    const float* proj_w = (const float*)d_in[4];
    const float* proj_b = (const float*)d_in[5];
    const float* nq_g   = (const float*)d_in[6];
    const float* nq_b   = (const float*)d_in[7];
    const float* nk_g   = (const float*)d_in[8];
    const float* nk_b   = (const float*)d_in[9];
    const float* conv_w = (const float*)d_in[10];
    const float* conv_b = (const float*)d_in[11];
    const float* ca1_w  = (const float*)d_in[12];
    const float* ca1_b  = (const float*)d_in[13];
    const float* ca2_w  = (const float*)d_in[14];
    const float* ca2_b  = (const float*)d_in[15];
    const float* mlp1_w = (const float*)d_in[16];
    const float* mlp1_b = (const float*)d_in[17];
    const float* mlp2_w = (const float*)d_in[18];
    const float* mlp2_b = (const float*)d_in[19];

    float* out0 = (float*)d_out;
    float* out1 = out0 + (size_t)4 * 1024 * 1024;

    char* ws = (char*)d_ws;
    size_t off = 0;
    auto alloc = [&](size_t bytes) -> char* {
        char* p = ws + off;
        off += (bytes + 255) & ~(size_t)255;
        return p;
    };
    __hip_bfloat16* xb     = (__hip_bfloat16*)alloc((size_t)MROWS * CDIM * 2);
    __hip_bfloat16* xmixb  = (__hip_bfloat16*)alloc((size_t)MROWS * CDIM * 2);
    float*          h1     = (float*)alloc((size_t)MROWS * 64 * 4);
    __hip_bfloat16* hb     = (__hip_bfloat16*)alloc((size_t)MROWS * 4096 * 2);
    __hip_bfloat16* qbb    = (__hip_bfloat16*)alloc((size_t)MROWS * CDIM * 2);
    __hip_bfloat16* kbb    = (__hip_bfloat16*)alloc((size_t)MROWS * CDIM * 2);
    __hip_bfloat16* vtb    = (__hip_bfloat16*)alloc((size_t)MROWS * CDIM * 2);
    __hip_bfloat16* aob    = (__hip_bfloat16*)alloc((size_t)MROWS * CDIM * 2);
    float*          amacc  = (float*)alloc(4096 * 4);
    __hip_bfloat16* wcat   = (__hip_bfloat16*)alloc((size_t)5120 * 1024 * 2);  // conv|mlp1
    __hip_bfloat16* qkvwb  = (__hip_bfloat16*)alloc((size_t)3145728 * 2);
    __hip_bfloat16* projwb = (__hip_bfloat16*)alloc((size_t)1048576 * 2);
    __hip_bfloat16* mlp2wb = (__hip_bfloat16*)alloc((size_t)4194304 * 2);

    // weight converts (conv rows 0..1023, mlp1 rows 1024..5119 of wcat)
    f2b<<<4096, 256, 0, stream>>>(conv_w, wcat, 1048576);
    f2b<<<16384, 256, 0, stream>>>(mlp1_w, wcat + (size_t)1048576, 4194304);
    f2b<<<12288, 256, 0, stream>>>(qkv_w, qkvwb, 3145728);
    f2b<<<4096, 256, 0, stream>>>(proj_w, projwb, 1048576);
    f2b<<<16384, 256, 0, stream>>>(mlp2_w, mlp2wb, 4194304);

    // prologue: x -> bf16 only
    mix_base<<<16384, 256, 0, stream>>>(x_list, xb, amacc);

    // fused conv+mlp1: cols<1024 -> xmixb (base mix + w2*gelu), cols>=1024 -> hb
    gemm_bf16<1, 4, 4><<<dim3(40, 32), 256, 0, stream>>>(
        xb, wcat, conv_b, nullptr, x_list, xmixb, hb, nullptr,
        nullptr, mlp1_b, nullptr, nullptr, wvec, MROWS, 5120, 1024);

    // channel attention: xmixb += w3*sig*x (bf16 rmw, after conv epilogue)
    ca1_kernel<<<256, 256, 0, stream>>>(xb, ca1_w, ca1_b, h1);
    ca2_kernel<<<dim3(256, 4), 256, 0, stream>>>(h1, ca2_w, ca2_b, xb, xmixb, wvec);

    // mlp2: xmixb += w5*(hb @ mlp2_w^T + b) (bf16 rmw)
    gemm_bf16<3, 4, 4><<<dim3(8, 32), 256, 0, stream>>>(
        hb, mlp2wb, mlp2_b, nullptr, nullptr, xmixb, nullptr, nullptr,
        nullptr, nullptr, nullptr, nullptr, wvec, MROWS, 1024, 4096);

    // qkv with fused per-head LN: q->qbb, k->kbb bf16 [b,h,n,d]; v->V^T bf16
    gemm_bf16<5, 4, 4><<<dim3(24, 32), 256, 0, stream>>>(
        xmixb, qkvwb, qkv_b, nullptr, nullptr, vtb, qbb, kbb,
        nq_g, nq_b, nk_g, nk_b, wvec, MROWS, 3072, 1024);

    // attention (MFMA)
    flash_mfma<<<dim3(64, 8), 256, 0, stream>>>(qbb, kbb, vtb, aob);

    // attn_map
    attn_map_acc<<<64, 256, 0, stream>>>(qbb, kbb, amacc);
    attn_map_out<<<16, 256, 0, stream>>>(amacc, out1);

    // projection + residual (residual from xmixb bf16)
    gemm_bf16<4, 4, 4><<<dim3(8, 32), 256, 0, stream>>>(
        aob, projwb, proj_b, out0, nullptr, nullptr, xmixb, nullptr,
        nullptr, nullptr, nullptr, nullptr, wvec, MROWS, 1024, 1024);
}